// Round 3
// baseline (665.495 us; speedup 1.0000x reference)
//
#include <hip/hip_runtime.h>

#define Vn 128
#define En 32
#define Hn 128
#define Bn 4
#define Sn 512
#define G4H 512   // 4*Hn

__device__ __forceinline__ float fsigmoid(float x) {
    // 1/(1+e^-x): e^-x may overflow to inf for very negative x -> 1/inf = 0, safe.
    return 1.0f / (1.0f + __expf(-x));
}

__device__ __forceinline__ float ftanh(float x) {
    // sign(x)*(1 - 2/(1+e^{2|x|})): e>=1 so never NaN, saturates to +-1.
    float ax = fabsf(x);
    float e  = __expf(2.0f * ax);
    float t  = 1.0f - 2.0f / (e + 1.0f);
    return copysignf(t, x);
}

// ---------------------------------------------------------------------------
// Kernel A: Gx[b][s][g] = (b_ih+b_hh)[g] + sum_e emb[x[b,s]][e] * W_ih[g][e]
// grid = B*S blocks, 512 threads (one per gate output)
// ---------------------------------------------------------------------------
__global__ __launch_bounds__(512) void k_embed_gates(
        const int* __restrict__ x, const float* __restrict__ emb,
        const float* __restrict__ Wih, const float* __restrict__ bih,
        const float* __restrict__ bhh, float* __restrict__ Gx) {
    int bs = blockIdx.x;
    int g  = threadIdx.x;
    __shared__ float e[En];
    if (g < En) e[g] = emb[x[bs] * En + g];
    __syncthreads();
    const float4* wr = (const float4*)(Wih + g * En);
    float acc = bih[g] + bhh[g];
#pragma unroll
    for (int i = 0; i < En / 4; i++) {
        float4 w4 = wr[i];
        acc += w4.x * e[4*i] + w4.y * e[4*i+1] + w4.z * e[4*i+2] + w4.w * e[4*i+3];
    }
    Gx[bs * G4H + g] = acc;
}

// ---------------------------------------------------------------------------
// Kernel B: LSTM recurrence. One block per batch (4 CUs), 512 threads.
// Thread tid: j = tid&127 (gate row within each gate type), q = tid>>7
// (K-quarter). Holds W_hh[g*128+j][32q..32q+32) in registers for g=0..3.
//
// R1/R2 post-mortem: compiler rematerialized the "register-resident" weight
// loads inside the step loop (VGPR_Count=88 both rounds despite
// __launch_bounds__(512,2)); per-step 256KB L1 re-read == measured 2012
// cyc/step. Fix: empty asm with "+v" on every weight component makes the
// loaded values opaque asm outputs -> remat illegal, weights must stay in
// VGPRs (~128 of the 256-per-wave budget at 2 waves/EU).
// ---------------------------------------------------------------------------
__global__ __launch_bounds__(512, 2) void k_lstm(
        const float* __restrict__ Whh, const float* __restrict__ Gx,
        float* __restrict__ out, float* __restrict__ hT, float* __restrict__ cT) {
    int b   = blockIdx.x;
    int tid = threadIdx.x;
    int j   = tid & 127;
    int q   = tid >> 7;

    __shared__ float hbuf[Hn];
    __shared__ float part[16][Hn];

    // loop-invariant weight preload: 32 float4 = 128 VGPRs
    float4 w[4][8];
#pragma unroll
    for (int g = 0; g < 4; g++) {
        const float4* row = (const float4*)(Whh + (g * Hn + j) * Hn + q * 32);
#pragma unroll
        for (int i = 0; i < 8; i++) w[g][i] = row[i];
    }
    // Pin: forbid rematerialization of the loads above.
#pragma unroll
    for (int g = 0; g < 4; g++) {
#pragma unroll
        for (int i = 0; i < 8; i++) {
            asm volatile("" : "+v"(w[g][i].x), "+v"(w[g][i].y),
                              "+v"(w[g][i].z), "+v"(w[g][i].w));
        }
    }

    float c = 0.0f;
    float hlast = 0.0f;
    if (tid < Hn) hbuf[tid] = 0.0f;
    __syncthreads();

    const float* gx_base  = Gx + b * Sn * G4H;
    float*       out_base = out + b * Sn * Hn;

    for (int s = 0; s < Sn; s++) {
        // prefetch Gx for this step (consumed after barrier -> latency hidden)
        float gx0 = 0.f, gx1 = 0.f, gx2 = 0.f, gx3 = 0.f;
        if (tid < Hn) {
            const float* gp = gx_base + s * G4H + j;
            gx0 = gp[0]; gx1 = gp[128]; gx2 = gp[256]; gx3 = gp[384];
        }
        // read this thread's 32-float h chunk (wave-uniform address: broadcast)
        float4 hv[8];
        const float4* h4 = ((const float4*)hbuf) + q * 8;
#pragma unroll
        for (int i = 0; i < 8; i++) hv[i] = h4[i];
        // 4 gate rows x 32-K partial dots
#pragma unroll
        for (int g = 0; g < 4; g++) {
            float a = 0.0f;
#pragma unroll
            for (int i = 0; i < 8; i++) {
                a += w[g][i].x * hv[i].x + w[g][i].y * hv[i].y
                   + w[g][i].z * hv[i].z + w[g][i].w * hv[i].w;
            }
            part[g * 4 + q][j] = a;
        }
        __syncthreads();
        if (tid < Hn) {
            float gi = gx0 + part[0][j]  + part[1][j]  + part[2][j]  + part[3][j];
            float gf = gx1 + part[4][j]  + part[5][j]  + part[6][j]  + part[7][j];
            float gg = gx2 + part[8][j]  + part[9][j]  + part[10][j] + part[11][j];
            float go = gx3 + part[12][j] + part[13][j] + part[14][j] + part[15][j];
            c = fsigmoid(gf) * c + fsigmoid(gi) * ftanh(gg);
            float h = fsigmoid(go) * ftanh(c);
            hlast = h;
            hbuf[j] = h;
            out_base[s * Hn + j] = h;
        }
        __syncthreads();
    }
    if (tid < Hn) {
        hT[b * Hn + j] = hlast;
        cT[b * Hn + j] = c;
    }
}

// ---------------------------------------------------------------------------
// Kernel C: q = out@Wq.T + bq ; k = out@Wk.T + bk
// grid = B*S blocks, 256 threads (128 for q, 128 for k)
// ---------------------------------------------------------------------------
__global__ __launch_bounds__(256) void k_qk(
        const float* __restrict__ out, const float* __restrict__ Wq,
        const float* __restrict__ bq, const float* __restrict__ Wk,
        const float* __restrict__ bk, float* __restrict__ qo, float* __restrict__ ko) {
    int bs  = blockIdx.x;
    int tid = threadIdx.x;
    __shared__ float o[Hn];
    if (tid < Hn) o[tid] = out[bs * Hn + tid];
    __syncthreads();
    int h = tid & 127;
    const float* Wm = (tid < Hn) ? Wq : Wk;
    const float* bm = (tid < Hn) ? bq : bk;
    const float4* wr = (const float4*)(Wm + h * Hn);
    float acc = bm[h];
#pragma unroll
    for (int i = 0; i < Hn / 4; i++) {
        float4 w4 = wr[i];
        acc += w4.x * o[4*i] + w4.y * o[4*i+1] + w4.z * o[4*i+2] + w4.w * o[4*i+3];
    }
    float* dst = (tid < Hn) ? qo : ko;
    dst[bs * Hn + h] = acc;
}

// ---------------------------------------------------------------------------
// Kernel D: Bahdanau scores + causal softmax + ctx. Block per (b,t),
// 512 threads: exactly one score row index i per thread (t <= 511), so the
// score/tanh phase is loop-free. ctx phase: 16-way i-split x 32 float4
// columns, combined through LDS part[16][128].
// ---------------------------------------------------------------------------
__global__ __launch_bounds__(512) void k_attn(
        const float* __restrict__ qo, const float* __restrict__ ko,
        const float* __restrict__ vvec, const float* __restrict__ out,
        float* __restrict__ ctx) {
    int b   = blockIdx.x >> 9;
    int t   = blockIdx.x & (Sn - 1);
    int tid = threadIdx.x;
    __shared__ float qs[Hn];
    __shared__ float vs[Hn];
    __shared__ float sc[Sn];
    __shared__ float red[512];
    __shared__ float part[16][Hn];

    if (tid < Hn) {
        qs[tid] = qo[(b * Sn + t) * Hn + tid];
        vs[tid] = vvec[tid];
    }
    __syncthreads();

    // --- scores: thread tid handles key index i = tid (if <= t) ---
    float a = -1e30f;
    if (tid <= t) {
        const float4* kr = (const float4*)(ko + (b * Sn + tid) * Hn);
        float s = 0.0f;
#pragma unroll
        for (int u = 0; u < Hn / 4; u++) {
            float4 k4 = kr[u];
            s += vs[4*u]   * ftanh(qs[4*u]   + k4.x);
            s += vs[4*u+1] * ftanh(qs[4*u+1] + k4.y);
            s += vs[4*u+2] * ftanh(qs[4*u+2] + k4.z);
            s += vs[4*u+3] * ftanh(qs[4*u+3] + k4.w);
        }
        sc[tid] = s;
        a = s;
    }
    red[tid] = a;
    __syncthreads();
    for (int off = 256; off > 0; off >>= 1) {
        if (tid < off) red[tid] = fmaxf(red[tid], red[tid + off]);
        __syncthreads();
    }
    float m = red[0];
    __syncthreads();

    float ev = 0.0f;
    if (tid <= t) {
        ev = __expf(sc[tid] - m);
        sc[tid] = ev;
    }
    red[tid] = ev;
    __syncthreads();
    for (int off = 256; off > 0; off >>= 1) {
        if (tid < off) red[tid] += red[tid + off];
        __syncthreads();
    }
    float inv = 1.0f / red[0];
    __syncthreads();

    // --- ctx: i-slice = tid>>5 (16 slices), float4 column = tid&31 ---
    int hq = tid & 31;
    int is = tid >> 5;
    float4 acc = {0.0f, 0.0f, 0.0f, 0.0f};
    const float4* ob = (const float4*)(out + b * Sn * Hn);
    for (int i = is; i <= t; i += 16) {
        float s = sc[i];
        float4 o4 = ob[i * (Hn / 4) + hq];
        acc.x += s * o4.x; acc.y += s * o4.y;
        acc.z += s * o4.z; acc.w += s * o4.w;
    }
    ((float4*)part[is])[hq] = acc;
    __syncthreads();
    if (tid < Hn) {
        float ssum = 0.0f;
#pragma unroll
        for (int r = 0; r < 16; r++) ssum += part[r][tid];
        ctx[(b * Sn + t) * Hn + tid] = ssum * inv;
    }
}

// ---------------------------------------------------------------------------
// Kernel E: logits = [out, ctx] @ Wf.T + bf. Block per (b,s), 128 threads.
// ---------------------------------------------------------------------------
__global__ __launch_bounds__(128) void k_final(
        const float* __restrict__ out, const float* __restrict__ ctx,
        const float* __restrict__ Wf, const float* __restrict__ bf,
        float* __restrict__ logits) {
    int bs  = blockIdx.x;
    int tid = threadIdx.x;  // = vocab index
    __shared__ float oc[2 * Hn];
    oc[tid]      = out[bs * Hn + tid];
    oc[tid + Hn] = ctx[bs * Hn + tid];
    __syncthreads();
    const float4* wr = (const float4*)(Wf + tid * 2 * Hn);
    float acc = bf[tid];
#pragma unroll
    for (int i = 0; i < (2 * Hn) / 4; i++) {
        float4 w4 = wr[i];
        acc += w4.x * oc[4*i] + w4.y * oc[4*i+1] + w4.z * oc[4*i+2] + w4.w * oc[4*i+3];
    }
    logits[bs * Vn + tid] = acc;
}

extern "C" void kernel_launch(void* const* d_in, const int* in_sizes, int n_in,
                              void* d_out, int out_size, void* d_ws, size_t ws_size,
                              hipStream_t stream) {
    const int*   x   = (const int*)d_in[0];
    const float* emb = (const float*)d_in[1];
    const float* Wih = (const float*)d_in[2];
    const float* Whh = (const float*)d_in[3];
    const float* bih = (const float*)d_in[4];
    const float* bhh = (const float*)d_in[5];
    const float* Wq  = (const float*)d_in[6];
    const float* bq  = (const float*)d_in[7];
    const float* Wk  = (const float*)d_in[8];
    const float* bk  = (const float*)d_in[9];
    const float* v   = (const float*)d_in[10];
    const float* Wf  = (const float*)d_in[11];
    const float* bf  = (const float*)d_in[12];

    float* logits = (float*)d_out;                 // (B,S,V) = 262144
    float* hT     = logits + Bn * Sn * Vn;         // (B,H)   = 512
    float* cT     = hT + Bn * Hn;                  // (B,H)   = 512

    float* ws   = (float*)d_ws;
    float* Gx   = ws;                               // B*S*4H = 1048576 floats
    float* outb = ws + 1048576;                     // B*S*H  = 262144
    float* qo   = ws + 1048576 + 262144;
    float* ko   = ws + 1048576 + 2 * 262144;
    float* ctx  = ws + 1048576 + 3 * 262144;

    k_embed_gates<<<Bn * Sn, 512, 0, stream>>>(x, emb, Wih, bih, bhh, Gx);
    k_lstm<<<Bn, 512, 0, stream>>>(Whh, Gx, outb, hT, cT);
    k_qk<<<Bn * Sn, 256, 0, stream>>>(outb, Wq, bq, Wk, bk, qo, ko);
    k_attn<<<Bn * Sn, 512, 0, stream>>>(qo, ko, v, outb, ctx);
    k_final<<<Bn * Sn, 128, 0, stream>>>(outb, ctx, Wf, bf, logits);
}

// Round 4
// 637.543 us; speedup vs baseline: 1.0438x; 1.0438x over previous
//
#include <hip/hip_runtime.h>

#define Vn 128
#define En 32
#define Hn 128
#define Bn 4
#define Sn 512
#define G4H 512   // 4*Hn

__device__ __forceinline__ float fsigmoid(float x) {
    // 1/(1+e^-x): e^-x may overflow to inf for very negative x -> 1/inf = 0, safe.
    return 1.0f / (1.0f + __expf(-x));
}

__device__ __forceinline__ float ftanh(float x) {
    // sign(x)*(1 - 2/(1+e^{2|x|})): e>=1 so never NaN, saturates to +-1.
    float ax = fabsf(x);
    float e  = __expf(2.0f * ax);
    float t  = 1.0f - 2.0f / (e + 1.0f);
    return copysignf(t, x);
}

// ---------------------------------------------------------------------------
// Kernel A': Gtab[v][g] = (b_ih+b_hh)[g] + sum_e emb[v][e] * W_ih[g][e]
// Only V=128 distinct embedding rows exist -> precompute per-vocab gate
// pre-activations once (128 blocks) instead of per-(b,s) (2048 blocks, which
// re-read all of W_ih per block = 128 MB of L2 traffic in R1-R3).
// ---------------------------------------------------------------------------
__global__ __launch_bounds__(512) void k_gtab(
        const float* __restrict__ emb, const float* __restrict__ Wih,
        const float* __restrict__ bih, const float* __restrict__ bhh,
        float* __restrict__ Gtab) {
    int v = blockIdx.x;
    int g = threadIdx.x;
    __shared__ float e[En];
    if (g < En) e[g] = emb[v * En + g];
    __syncthreads();
    const float4* wr = (const float4*)(Wih + g * En);
    float acc = bih[g] + bhh[g];
#pragma unroll
    for (int i = 0; i < En / 4; i++) {
        float4 w4 = wr[i];
        acc += w4.x * e[4*i] + w4.y * e[4*i+1] + w4.z * e[4*i+2] + w4.w * e[4*i+3];
    }
    Gtab[v * G4H + g] = acc;
}

// ---------------------------------------------------------------------------
// Kernel B: LSTM recurrence. One block per batch (4 CUs), 512 threads.
// Thread tid: j = tid&127 (gate row within each gate type), q = tid>>7
// (K-quarter). Holds W_hh[g*128+j][32q..32q+32) in registers for g=0..3.
//
// R1-R3 post-mortem: Whh loads are invariant -> LLVM rematerialized them
// inside the step loop to chase occupancy ABOVE the launch_bounds minimum
// (VGPR_Count stayed 88-92); 256KB/step L1/L2 re-read == measured 2012
// cyc/step. Fix: amdgpu_waves_per_eu(2,2) caps max occupancy at 2 waves/EU
// (VGPR budget 256, nothing to gain from remat), plus the "+v" pin now sits
// INSIDE the loop making the weights a loop-carried opaque dependence, so
// remat from Whh is illegal.
// ---------------------------------------------------------------------------
__global__ __attribute__((amdgpu_flat_work_group_size(512, 512),
                          amdgpu_waves_per_eu(2, 2)))
void k_lstm(
        const float* __restrict__ Whh, const float* __restrict__ Gtab,
        const int* __restrict__ x,
        float* __restrict__ out, float* __restrict__ hT, float* __restrict__ cT) {
    int b   = blockIdx.x;
    int tid = threadIdx.x;
    int j   = tid & 127;
    int q   = tid >> 7;

    __shared__ float hbuf[Hn];
    __shared__ float part[16][Hn];
    __shared__ int   xb[Sn];

    // token ids for this batch (uniform per step, broadcast from LDS)
    xb[tid] = x[b * Sn + tid];

    // loop-invariant weight preload: 32 float4 = 128 VGPRs
    float4 w[4][8];
#pragma unroll
    for (int g = 0; g < 4; g++) {
        const float4* row = (const float4*)(Whh + (g * Hn + j) * Hn + q * 32);
#pragma unroll
        for (int i = 0; i < 8; i++) w[g][i] = row[i];
    }

    float c = 0.0f;
    float hlast = 0.0f;
    if (tid < Hn) hbuf[tid] = 0.0f;
    __syncthreads();

    float* out_base = out + b * Sn * Hn;

    for (int s = 0; s < Sn; s++) {
        // Loop-carried pin: w regs are opaque asm outputs each iteration ->
        // compiler cannot rematerialize the Whh loads.
#pragma unroll
        for (int g = 0; g < 4; g++) {
#pragma unroll
            for (int i = 0; i < 8; i++) {
                asm volatile("" : "+v"(w[g][i].x), "+v"(w[g][i].y),
                                  "+v"(w[g][i].z), "+v"(w[g][i].w));
            }
        }
        // prefetch gate pre-activations for this step from the vocab table
        float gx0 = 0.f, gx1 = 0.f, gx2 = 0.f, gx3 = 0.f;
        if (tid < Hn) {
            const float* gp = Gtab + xb[s] * G4H + j;
            gx0 = gp[0]; gx1 = gp[128]; gx2 = gp[256]; gx3 = gp[384];
        }
        // read this thread's 32-float h chunk (wave-uniform address: broadcast)
        float4 hv[8];
        const float4* h4 = ((const float4*)hbuf) + q * 8;
#pragma unroll
        for (int i = 0; i < 8; i++) hv[i] = h4[i];
        // 4 gate rows x 32-K partial dots
#pragma unroll
        for (int g = 0; g < 4; g++) {
            float a = 0.0f;
#pragma unroll
            for (int i = 0; i < 8; i++) {
                a += w[g][i].x * hv[i].x + w[g][i].y * hv[i].y
                   + w[g][i].z * hv[i].z + w[g][i].w * hv[i].w;
            }
            part[g * 4 + q][j] = a;
        }
        __syncthreads();
        if (tid < Hn) {
            float gi = gx0 + part[0][j]  + part[1][j]  + part[2][j]  + part[3][j];
            float gf = gx1 + part[4][j]  + part[5][j]  + part[6][j]  + part[7][j];
            float gg = gx2 + part[8][j]  + part[9][j]  + part[10][j] + part[11][j];
            float go = gx3 + part[12][j] + part[13][j] + part[14][j] + part[15][j];
            c = fsigmoid(gf) * c + fsigmoid(gi) * ftanh(gg);
            float h = fsigmoid(go) * ftanh(c);
            hlast = h;
            hbuf[j] = h;
            out_base[s * Hn + j] = h;
        }
        __syncthreads();
    }
    if (tid < Hn) {
        hT[b * Hn + j] = hlast;
        cT[b * Hn + j] = c;
    }
}

// ---------------------------------------------------------------------------
// Kernel C: q = out@Wq.T + bq ; k = out@Wk.T + bk
// grid = B*S blocks, 256 threads (128 for q, 128 for k)
// ---------------------------------------------------------------------------
__global__ __launch_bounds__(256) void k_qk(
        const float* __restrict__ out, const float* __restrict__ Wq,
        const float* __restrict__ bq, const float* __restrict__ Wk,
        const float* __restrict__ bk, float* __restrict__ qo, float* __restrict__ ko) {
    int bs  = blockIdx.x;
    int tid = threadIdx.x;
    __shared__ float o[Hn];
    if (tid < Hn) o[tid] = out[bs * Hn + tid];
    __syncthreads();
    int h = tid & 127;
    const float* Wm = (tid < Hn) ? Wq : Wk;
    const float* bm = (tid < Hn) ? bq : bk;
    const float4* wr = (const float4*)(Wm + h * Hn);
    float acc = bm[h];
#pragma unroll
    for (int i = 0; i < Hn / 4; i++) {
        float4 w4 = wr[i];
        acc += w4.x * o[4*i] + w4.y * o[4*i+1] + w4.z * o[4*i+2] + w4.w * o[4*i+3];
    }
    float* dst = (tid < Hn) ? qo : ko;
    dst[bs * Hn + h] = acc;
}

// ---------------------------------------------------------------------------
// Kernel D: Bahdanau scores + causal softmax + ctx. Block per (b,t),
// 512 threads: exactly one score row index i per thread (t <= 511), so the
// score/tanh phase is loop-free. ctx phase: 16-way i-split x 32 float4
// columns, combined through LDS part[16][128].
// ---------------------------------------------------------------------------
__global__ __launch_bounds__(512) void k_attn(
        const float* __restrict__ qo, const float* __restrict__ ko,
        const float* __restrict__ vvec, const float* __restrict__ out,
        float* __restrict__ ctx) {
    int b   = blockIdx.x >> 9;
    int t   = blockIdx.x & (Sn - 1);
    int tid = threadIdx.x;
    __shared__ float qs[Hn];
    __shared__ float vs[Hn];
    __shared__ float sc[Sn];
    __shared__ float red[512];
    __shared__ float part[16][Hn];

    if (tid < Hn) {
        qs[tid] = qo[(b * Sn + t) * Hn + tid];
        vs[tid] = vvec[tid];
    }
    __syncthreads();

    // --- scores: thread tid handles key index i = tid (if <= t) ---
    float a = -1e30f;
    if (tid <= t) {
        const float4* kr = (const float4*)(ko + (b * Sn + tid) * Hn);
        float s = 0.0f;
#pragma unroll
        for (int u = 0; u < Hn / 4; u++) {
            float4 k4 = kr[u];
            s += vs[4*u]   * ftanh(qs[4*u]   + k4.x);
            s += vs[4*u+1] * ftanh(qs[4*u+1] + k4.y);
            s += vs[4*u+2] * ftanh(qs[4*u+2] + k4.z);
            s += vs[4*u+3] * ftanh(qs[4*u+3] + k4.w);
        }
        sc[tid] = s;
        a = s;
    }
    red[tid] = a;
    __syncthreads();
    for (int off = 256; off > 0; off >>= 1) {
        if (tid < off) red[tid] = fmaxf(red[tid], red[tid + off]);
        __syncthreads();
    }
    float m = red[0];
    __syncthreads();

    float ev = 0.0f;
    if (tid <= t) {
        ev = __expf(sc[tid] - m);
        sc[tid] = ev;
    }
    red[tid] = ev;
    __syncthreads();
    for (int off = 256; off > 0; off >>= 1) {
        if (tid < off) red[tid] += red[tid + off];
        __syncthreads();
    }
    float inv = 1.0f / red[0];
    __syncthreads();

    // --- ctx: i-slice = tid>>5 (16 slices), float4 column = tid&31 ---
    int hq = tid & 31;
    int is = tid >> 5;
    float4 acc = {0.0f, 0.0f, 0.0f, 0.0f};
    const float4* ob = (const float4*)(out + b * Sn * Hn);
    for (int i = is; i <= t; i += 16) {
        float s = sc[i];
        float4 o4 = ob[i * (Hn / 4) + hq];
        acc.x += s * o4.x; acc.y += s * o4.y;
        acc.z += s * o4.z; acc.w += s * o4.w;
    }
    ((float4*)part[is])[hq] = acc;
    __syncthreads();
    if (tid < Hn) {
        float ssum = 0.0f;
#pragma unroll
        for (int r = 0; r < 16; r++) ssum += part[r][tid];
        ctx[(b * Sn + t) * Hn + tid] = ssum * inv;
    }
}

// ---------------------------------------------------------------------------
// Kernel E: logits = [out, ctx] @ Wf.T + bf. Block per (b,s), 128 threads.
// ---------------------------------------------------------------------------
__global__ __launch_bounds__(128) void k_final(
        const float* __restrict__ out, const float* __restrict__ ctx,
        const float* __restrict__ Wf, const float* __restrict__ bf,
        float* __restrict__ logits) {
    int bs  = blockIdx.x;
    int tid = threadIdx.x;  // = vocab index
    __shared__ float oc[2 * Hn];
    oc[tid]      = out[bs * Hn + tid];
    oc[tid + Hn] = ctx[bs * Hn + tid];
    __syncthreads();
    const float4* wr = (const float4*)(Wf + tid * 2 * Hn);
    float acc = bf[tid];
#pragma unroll
    for (int i = 0; i < (2 * Hn) / 4; i++) {
        float4 w4 = wr[i];
        acc += w4.x * oc[4*i] + w4.y * oc[4*i+1] + w4.z * oc[4*i+2] + w4.w * oc[4*i+3];
    }
    logits[bs * Vn + tid] = acc;
}

extern "C" void kernel_launch(void* const* d_in, const int* in_sizes, int n_in,
                              void* d_out, int out_size, void* d_ws, size_t ws_size,
                              hipStream_t stream) {
    const int*   x   = (const int*)d_in[0];
    const float* emb = (const float*)d_in[1];
    const float* Wih = (const float*)d_in[2];
    const float* Whh = (const float*)d_in[3];
    const float* bih = (const float*)d_in[4];
    const float* bhh = (const float*)d_in[5];
    const float* Wq  = (const float*)d_in[6];
    const float* bq  = (const float*)d_in[7];
    const float* Wk  = (const float*)d_in[8];
    const float* bk  = (const float*)d_in[9];
    const float* v   = (const float*)d_in[10];
    const float* Wf  = (const float*)d_in[11];
    const float* bf  = (const float*)d_in[12];

    float* logits = (float*)d_out;                 // (B,S,V) = 262144
    float* hT     = logits + Bn * Sn * Vn;         // (B,H)   = 512
    float* cT     = hT + Bn * Hn;                  // (B,H)   = 512

    float* ws   = (float*)d_ws;
    float* Gtab = ws;                               // V*4H   = 65536 floats
    float* outb = ws + 65536;                       // B*S*H  = 262144
    float* qo   = ws + 65536 + 262144;
    float* ko   = ws + 65536 + 2 * 262144;
    float* ctx  = ws + 65536 + 3 * 262144;

    k_gtab<<<Vn, 512, 0, stream>>>(emb, Wih, bih, bhh, Gtab);
    k_lstm<<<Bn, 512, 0, stream>>>(Whh, Gtab, x, outb, hT, cT);
    k_qk<<<Bn * Sn, 256, 0, stream>>>(outb, Wq, bq, Wk, bk, qo, ko);
    k_attn<<<Bn * Sn, 512, 0, stream>>>(qo, ko, v, outb, ctx);
    k_final<<<Bn * Sn, 128, 0, stream>>>(outb, ctx, Wf, bf, logits);
}